// Round 10
// baseline (235.550 us; speedup 1.0000x reference)
//
#include <hip/hip_runtime.h>
#include <hip/hip_bf16.h>
#include <stdint.h>
#include <math.h>

// Sizes fixed by the problem.
#define BB   8
#define NN_  1024
#define CC   768
#define HH   12
#define HDD  64

typedef __attribute__((ext_vector_type(8))) short bf16x8;   // 8 bf16 (4 VGPRs)
typedef __attribute__((ext_vector_type(4))) float f32x4;    // 16x16 MFMA acc
typedef __attribute__((ext_vector_type(16))) float f32x16;  // 32x32 MFMA acc
typedef __attribute__((ext_vector_type(4))) float f32x4v;
typedef __attribute__((ext_vector_type(4))) unsigned short u16x4;

union FragU { unsigned int u[4]; bf16x8 b; };

__device__ __forceinline__ unsigned short f2bf(float f) {
    union { float f; unsigned int u; } v; v.f = f;
    unsigned int r = v.u + 0x7fffu + ((v.u >> 16) & 1u);   // RNE
    return (unsigned short)(r >> 16);
}

#define CVTPK(d_, a_, b_) asm("v_cvt_pk_bf16_f32 %0, %1, %2" : "=v"(d_) : "v"(a_), "v"(b_))
#define SWAP32(a_, b_) asm("v_permlane32_swap_b32 %0, %1" : "+v"(a_), "+v"(b_))

#define GLDS(g_, l_) __builtin_amdgcn_global_load_lds( \
    (const __attribute__((address_space(1))) void*)(g_), \
    (__attribute__((address_space(3))) void*)(l_), 16, 0, 0)

// Transform a 32x32 C'-tile (col=lane&31, crow=(r&3)+8*(r>>2)+4*hi5) held as
// 16 lane-local floats into two bf16 A-frags [row=col][k=crow 0..15 / 16..31].
#define MKFRAGS(P_, F0_, F1_) do {                                             \
    unsigned int c0,c1,c2,c3,c4,c5,c6,c7;                                      \
    CVTPK(c0, P_[0],  P_[1]);  CVTPK(c1, P_[2],  P_[3]);                       \
    CVTPK(c2, P_[4],  P_[5]);  CVTPK(c3, P_[6],  P_[7]);                       \
    CVTPK(c4, P_[8],  P_[9]);  CVTPK(c5, P_[10], P_[11]);                      \
    CVTPK(c6, P_[12], P_[13]); CVTPK(c7, P_[14], P_[15]);                      \
    SWAP32(c0, c2); SWAP32(c1, c3); SWAP32(c4, c6); SWAP32(c5, c7);            \
    FragU fu0_, fu1_;                                                          \
    fu0_.u[0]=c0; fu0_.u[1]=c1; fu0_.u[2]=c2; fu0_.u[3]=c3;                    \
    fu1_.u[0]=c4; fu1_.u[1]=c5; fu1_.u[2]=c6; fu1_.u[3]=c7;                    \
    F0_ = fu0_.b; F1_ = fu1_.b;                                                \
} while (0)

// ---------------------------------------------------------------- fused cvt
#define CVT_N0 1572864   // x
#define CVT_N1 2015232   // +Wqkv
#define CVT_N2 2162688   // +Wproj
#define CVT_N3 2163712   // +Wfc1
#define CVT_N4 2164736   // +Wfc2
__global__ void cvt_all(const float* __restrict__ x, const float* __restrict__ wqkv,
                        const float* __restrict__ wproj, const float* __restrict__ wf1,
                        const float* __restrict__ wf2,
                        unsigned short* __restrict__ xb, unsigned short* __restrict__ wqkvb,
                        unsigned short* __restrict__ wprojb, unsigned short* __restrict__ wf1b,
                        unsigned short* __restrict__ wf2b) {
    int i = blockIdx.x * blockDim.x + threadIdx.x;
    int stride = gridDim.x * blockDim.x;
    for (; i < CVT_N4; i += stride) {
        const f32x4v* src; u16x4* dst; int off;
        if (i < CVT_N0)      { src = (const f32x4v*)x;     dst = (u16x4*)xb;     off = i; }
        else if (i < CVT_N1) { src = (const f32x4v*)wqkv;  dst = (u16x4*)wqkvb;  off = i - CVT_N0; }
        else if (i < CVT_N2) { src = (const f32x4v*)wproj; dst = (u16x4*)wprojb; off = i - CVT_N1; }
        else if (i < CVT_N3) { src = (const f32x4v*)wf1;   dst = (u16x4*)wf1b;   off = i - CVT_N2; }
        else                 { src = (const f32x4v*)wf2;   dst = (u16x4*)wf2b;   off = i - CVT_N3; }
        f32x4v v = src[off];
        u16x4 o;
        o.x = f2bf(v.x); o.y = f2bf(v.y); o.z = f2bf(v.z); o.w = f2bf(v.w);
        dst[off] = o;
    }
}

// ---------------------------------------------------------------- QKV+spk GEMM
// r9 skeleton, but X (B-operand) bypasses LDS entirely: its MFMA frag is 8
// consecutive k at one token row = a direct 16B global load per lane, from the
// L2-resident X-tile (r9 locality). LDS now holds only the Wqkv A-tiles
// (4 buf x 16KB = 64KB -> 2 blocks/CU). Per-phase LDS port traffic drops
// 88KB -> 48KB (the measured ~2500cy/phase floor's biggest term). X-frags are
// prefetched 2 phases ahead into ping-pong regs, issued AFTER the MFMA cluster
// (WAR-safe: in-order issue), covered by counted vmcnt(8).
__global__ __launch_bounds__(512, 4)
void qkv_spk_gemm(const unsigned short* __restrict__ Xg,
                  const unsigned short* __restrict__ Wqkv,
                  const unsigned short* __restrict__ Wf1,
                  const unsigned short* __restrict__ Wf2,
                  const float* __restrict__ bf1,
                  const float* __restrict__ bf2,
                  unsigned short* __restrict__ Rq,
                  unsigned short* __restrict__ Rk,
                  unsigned short* __restrict__ VT) {
    __shared__ short sA[4][8192];   // 4 x 16KB: 256 feat x 32 k  (total 64KB)

    const int t    = threadIdx.x;       // 0..511
    const int wid  = t >> 6;            // 0..7
    const int lane = t & 63;
    const int l31  = lane & 31;
    const int hi5  = lane >> 5;
    const int fw   = wid >> 1;          // feat quarter 0..3 (64 feats each)
    const int wn   = wid & 1;           // tok half 0..1 (64 tokens each)

    // L2-reuse-swapped XCD mapping (r9): bijective over 576 = 8 x 8g x 9f.
    const int bid  = (int)blockIdx.x;
    const int c    = bid & 7;
    const int j    = bid >> 3;
    const int f_   = j % 9;
    const int g_   = j / 9;
    const int bx   = c * 8 + g_;
    const int by   = f_;
    const int F0   = by * 256;
    const int T0   = bx * 128;

    const int xrow = T0 + wn * 64 + l31;   // + tb*32
    const int xcol8 = hi5 * 8;

    // Stage A-tile kt (2 loads/thread), double-row packed, XOR-swizzled.
#define STGA(bi_, kt_) do {                                                    \
    _Pragma("unroll")                                                          \
    for (int i = 0; i < 2; i++) {                                              \
        int li_ = i * 512 + t;                                                 \
        int dr_ = li_ >> 3;                                                    \
        int u_  = (li_ & 7) ^ (dr_ & 7);                                       \
        GLDS(Wqkv + (size_t)(F0 + dr_ * 2 + (u_ >> 2)) * 768 + (kt_) * 32 + (u_ & 3) * 8, \
             &sA[bi_][li_ * 8]);                                               \
    }                                                                          \
} while (0)

    // X frags direct from global (L2-hot): 4 x 16B gather per thread.
#define XLD(X_, kt_) do {                                                      \
    _Pragma("unroll")                                                          \
    for (int tb = 0; tb < 2; tb++)                                             \
        _Pragma("unroll")                                                      \
        for (int ks = 0; ks < 2; ks++)                                         \
            X_[tb][ks] = *(const bf16x8*)&Xg[(size_t)(xrow + tb * 32) * 768 +  \
                                             (kt_) * 32 + ks * 16 + xcol8];    \
} while (0)

    f32x16 acc[2][2];
#pragma unroll
    for (int fb = 0; fb < 2; fb++)
#pragma unroll
        for (int tb = 0; tb < 2; tb++)
#pragma unroll
            for (int r = 0; r < 16; r++) acc[fb][tb][r] = 0.f;

    bf16x8 wA[2][2], wB[2][2], xA[2][2], xB[2][2];   // named sets (rule #20)

#define RDA(W_, bc_) do {                                                      \
    const char* ab_ = (const char*)sA[bc_];                                    \
    _Pragma("unroll")                                                          \
    for (int fb = 0; fb < 2; fb++) {                                           \
        int r_ = fw * 64 + fb * 32 + l31;                                      \
        int dr_ = r_ >> 1;                                                     \
        _Pragma("unroll")                                                      \
        for (int ks = 0; ks < 2; ks++)                                         \
            W_[fb][ks] = *(const bf16x8*)(ab_ + dr_ * 128 +                    \
                ((((r_ & 1) * 4 + ks * 2 + hi5) ^ (dr_ & 7)) << 4));           \
    }                                                                          \
} while (0)

#define MFMA8(W_, X_)                                                          \
    _Pragma("unroll")                                                          \
    for (int ks = 0; ks < 2; ks++)                                             \
        _Pragma("unroll")                                                      \
        for (int fb = 0; fb < 2; fb++)                                         \
            _Pragma("unroll")                                                  \
            for (int tb = 0; tb < 2; tb++)                                     \
                acc[fb][tb] = __builtin_amdgcn_mfma_f32_32x32x16_bf16(         \
                    W_[fb][ks], X_[tb][ks], acc[fb][tb], 0, 0, 0)

    // Phase t: STGA(t+3) -> vmcnt -> barrier -> RDA(t+1) -> MFMA(t) ->
    // XLD(t+2 -> just-freed X set) -> lgkm0.
#define PH(CW_, CX_, NW_, rb_, sb_, t_, VM_) do {                              \
    if ((t_) + 3 < 24) STGA(sb_, (t_) + 3);                                    \
    asm volatile("s_waitcnt vmcnt(" #VM_ ")" ::: "memory");                    \
    __builtin_amdgcn_s_barrier();                                              \
    if ((t_) + 1 < 24) RDA(NW_, rb_);                                          \
    __builtin_amdgcn_sched_barrier(0);                                         \
    __builtin_amdgcn_s_setprio(1);                                             \
    MFMA8(CW_, CX_);                                                           \
    __builtin_amdgcn_s_setprio(0);                                             \
    if ((t_) + 2 < 24) XLD(CX_, (t_) + 2);                                     \
    asm volatile("s_waitcnt lgkmcnt(0)" ::: "memory");                         \
} while (0)

    // Prologue: A(0..2) staged, X(0)->xA, X(1)->xB; drain A(0..2)+X(0).
    STGA(0, 0); STGA(1, 1); STGA(2, 2);
    XLD(xA, 0); XLD(xB, 1);
    asm volatile("s_waitcnt vmcnt(4)" ::: "memory");
    __builtin_amdgcn_s_barrier();
    RDA(wA, 0);
    asm volatile("s_waitcnt lgkmcnt(0)" ::: "memory");

#pragma unroll 1
    for (int t4 = 0; t4 < 20; t4 += 4) {
        PH(wA, xA, wB, 1, 3, t4 + 0, 8);
        PH(wB, xB, wA, 2, 0, t4 + 1, 8);
        PH(wA, xA, wB, 3, 1, t4 + 2, 8);
        PH(wB, xB, wA, 0, 2, t4 + 3, 8);
    }
    PH(wA, xA, wB, 1, 3, 20, 8);
    PH(wB, xB, wA, 2, 0, 21, 6);
    PH(wA, xA, wB, 3, 1, 22, 4);
    PH(wB, xB, wA, 0, 2, 23, 0);
#undef PH
#undef MFMA8
#undef RDA
#undef XLD
#undef STGA

    // ---- epilogue (r5-r9 validated, wave = 64 feat x 64 tok) ----
    const int fbase = F0 + fw * 64;
    const int p  = fbase / 768;
    const int hh = (fbase - p * 768) >> 6;
    const int tok0 = T0 + wn * 64;       // 64-aligned -> single batch
    const int b  = tok0 >> 10;
    const int n0 = tok0 & 1023;
    const int crow0 = 4 * hi5;

    if (p == 2) {
        const size_t vtb = ((size_t)(b * HH + hh)) * HDD * NN_;
#pragma unroll
        for (int fb = 0; fb < 2; fb++)
#pragma unroll
            for (int tb = 0; tb < 2; tb++)
#pragma unroll
                for (int r = 0; r < 16; r++) {
                    int d = fb * 32 + (r & 3) + 8 * (r >> 2) + crow0;
                    int n = n0 + tb * 32 + l31;
                    VT[vtb + (size_t)d * NN_ + n] = f2bf(4.f * fmaxf(acc[fb][tb][r], 0.f));
                }
    } else {
        const unsigned short* Wf = p ? Wf2 : Wf1;
        const float* bfp = p ? bf2 : bf1;
        unsigned short* R = p ? Rk : Rq;
        bf16x8 wfr[2][4];
#pragma unroll
        for (int dh = 0; dh < 2; dh++)
#pragma unroll
            for (int ks = 0; ks < 4; ks++)
                wfr[dh][ks] = *(const bf16x8*)&Wf[(size_t)(dh * 32 + l31) * HDD + ks * 16 + hi5 * 8];
        float bv0 = bfp[l31], bv1 = bfp[32 + l31];
        const size_t qkb = ((size_t)(b * HH + hh)) * NN_ * HDD;
#pragma unroll
        for (int tb = 0; tb < 2; tb++) {
            float pv0[16], pv1[16];
#pragma unroll
            for (int r = 0; r < 16; r++) {
                pv0[r] = fmaxf(acc[0][tb][r], 0.f);
                pv1[r] = fmaxf(acc[1][tb][r], 0.f);
            }
            bf16x8 pa0, pa1, pa2, pa3;
            MKFRAGS(pv0, pa0, pa1);
            MKFRAGS(pv1, pa2, pa3);
            f32x16 D0, D1;
#pragma unroll
            for (int r = 0; r < 16; r++) { D0[r] = 0.f; D1[r] = 0.f; }
            D0 = __builtin_amdgcn_mfma_f32_32x32x16_bf16(pa0, wfr[0][0], D0, 0, 0, 0);
            D0 = __builtin_amdgcn_mfma_f32_32x32x16_bf16(pa1, wfr[0][1], D0, 0, 0, 0);
            D0 = __builtin_amdgcn_mfma_f32_32x32x16_bf16(pa2, wfr[0][2], D0, 0, 0, 0);
            D0 = __builtin_amdgcn_mfma_f32_32x32x16_bf16(pa3, wfr[0][3], D0, 0, 0, 0);
            D1 = __builtin_amdgcn_mfma_f32_32x32x16_bf16(pa0, wfr[1][0], D1, 0, 0, 0);
            D1 = __builtin_amdgcn_mfma_f32_32x32x16_bf16(pa1, wfr[1][1], D1, 0, 0, 0);
            D1 = __builtin_amdgcn_mfma_f32_32x32x16_bf16(pa2, wfr[1][2], D1, 0, 0, 0);
            D1 = __builtin_amdgcn_mfma_f32_32x32x16_bf16(pa3, wfr[1][3], D1, 0, 0, 0);
#pragma unroll
            for (int r = 0; r < 16; r++) {
                int n = n0 + tb * 32 + (r & 3) + 8 * (r >> 2) + crow0;
                size_t rowb = qkb + (size_t)n * HDD;
                R[rowb + l31]      = f2bf(D0[r] + bv0);
                R[rowb + 32 + l31] = f2bf(D1[r] + bv1);
            }
        }
    }
}

// ---------------------------------------------------------------- attention
// r3 structure + counted-vmcnt 3-buffer staging (r6 mechanism): STAGE(kt+2)
// at iter top, vmcnt(4) + raw s_barrier at bottom (was __syncthreads = drain0
// of the JUST-issued stage). Each stage now has a full iteration of cover.
__global__ __launch_bounds__(256, 2)
void attn_kernel(const unsigned short* __restrict__ Q,
                 const unsigned short* __restrict__ Kx,
                 const unsigned short* __restrict__ VT,
                 unsigned short* __restrict__ AO) {
    __shared__ short sK[3][4096];
    __shared__ short sV[3][4096];
    __shared__ float sinv[4][32];

    const int t    = threadIdx.x;
    const int lane = t & 63;
    const int wid  = t >> 6;
    const int l31  = lane & 31;
    const int hi5  = lane >> 5;

    const int bid = (int)blockIdx.x;
    const int lbid = (bid & 7) * 96 + (bid >> 3);
    const int bh = lbid >> 3;
    const int qt = lbid & 7;
    const int b = bh / HH, h = bh - b * HH;

    const unsigned short* Qs = Q  + (size_t)bh * NN_ * HDD;
    const unsigned short* Ks = Kx + (size_t)bh * NN_ * HDD;
    const unsigned short* Vt = VT + (size_t)bh * HDD * NN_;
    const int q0 = qt * 128 + wid * 32;

    bf16x8 qf[4];
#pragma unroll
    for (int ds = 0; ds < 4; ds++)
        qf[ds] = *(const bf16x8*)&Qs[(size_t)(q0 + l31) * HDD + ds * 16 + hi5 * 8];

    f32x16 O0, O1;
#pragma unroll
    for (int r = 0; r < 16; r++) { O0[r] = 0.f; O1[r] = 0.f; }
    float sumacc = 0.f;

    const int srow = t >> 3;
    const int sslot = t & 7;
    const int dstoff = ((t & 192)) * 8;

#define STAGE(buf_, kt_) do {                                                  \
    _Pragma("unroll")                                                          \
    for (int i = 0; i < 2; i++) {                                              \
        int row_ = srow + i * 32;                                              \
        int sl_  = (sslot ^ (row_ & 7)) << 3;                                  \
        const unsigned short* gk_ = Ks + (size_t)((kt_) * 64 + row_) * HDD + sl_; \
        const unsigned short* gv_ = Vt + (size_t)row_ * NN_ + (kt_) * 64 + sl_;   \
        GLDS(gk_, &sK[buf_][i * 2048 + dstoff]);                               \
        GLDS(gv_, &sV[buf_][i * 2048 + dstoff]);                               \
    }                                                                          \
} while (0)

#define ABODY(cb_, sb_, kt_, VM_) do {                                         \
    if ((kt_) + 2 < 16) STAGE(sb_, (kt_) + 2);                                 \
    const char* kbase = (const char*)&sK[cb_][0];                              \
    const char* vbase = (const char*)&sV[cb_][0];                              \
    bf16x8 vbf[4][2];                                                          \
    _Pragma("unroll")                                                          \
    for (int ks = 0; ks < 4; ks++)                                             \
        _Pragma("unroll")                                                      \
        for (int dt = 0; dt < 2; dt++) {                                       \
            int d = dt * 32 + l31;                                             \
            vbf[ks][dt] = *(const bf16x8*)(vbase + d * 128 +                   \
                           ((ks * 32 + hi5 * 16) ^ ((d & 7) << 4)));           \
        }                                                                      \
    bf16x8 ka[2][4];                                                           \
    _Pragma("unroll")                                                          \
    for (int kt2 = 0; kt2 < 2; kt2++)                                          \
        _Pragma("unroll")                                                      \
        for (int ds = 0; ds < 4; ds++) {                                       \
            int kk = kt2 * 32 + l31;                                           \
            ka[kt2][ds] = *(const bf16x8*)(kbase + kk * 128 +                  \
                           ((ds * 32 + hi5 * 16) ^ ((kk & 7) << 4)));          \
        }                                                                      \
    f32x16 S0, S1;                                                             \
    _Pragma("unroll")                                                          \
    for (int r = 0; r < 16; r++) { S0[r] = 0.f; S1[r] = 0.f; }                 \
    _Pragma("unroll")                                                          \
    for (int ds = 0; ds < 4; ds++) {                                           \
        S0 = __builtin_amdgcn_mfma_f32_32x32x16_bf16(ka[0][ds], qf[ds], S0, 0, 0, 0); \
        S1 = __builtin_amdgcn_mfma_f32_32x32x16_bf16(ka[1][ds], qf[ds], S1, 0, 0, 0); \
    }                                                                          \
    float p0[16], p1[16];                                                      \
    _Pragma("unroll")                                                          \
    for (int r = 0; r < 16; r++) {                                             \
        p0[r] = exp2f(0.36067376f * fmaxf(S0[r], 0.f));                        \
        p1[r] = exp2f(0.36067376f * fmaxf(S1[r], 0.f));                        \
    }                                                                          \
    float s0 = 0.f, s1 = 0.f;                                                  \
    _Pragma("unroll")                                                          \
    for (int r = 0; r < 16; r++) { s0 += p0[r]; s1 += p1[r]; }                 \
    sumacc += s0 + s1;                                                         \
    bf16x8 paf0, paf1, paf2, paf3;                                             \
    MKFRAGS(p0, paf0, paf1);                                                   \
    MKFRAGS(p1, paf2, paf3);                                                   \
    O0 = __builtin_amdgcn_mfma_f32_32x32x16_bf16(paf0, vbf[0][0], O0, 0, 0, 0);\
    O1 = __builtin_amdgcn_mfma_f32_32x32x16_bf16(paf0, vbf[0][1], O1, 0, 0, 0);\
    O0 = __builtin_amdgcn_mfma_f32_32x32x16_bf16(paf1, vbf[1][0], O0, 0, 0, 0);\
    O1 = __builtin_amdgcn_mfma_f32_32x32x16_bf16(paf1, vbf[1][1], O1, 0, 0, 0);\
    O0 = __builtin_amdgcn_mfma_f32_32x32x16_bf16(paf2, vbf[2][0], O0, 0, 0, 0);\
    O1 = __builtin_amdgcn_mfma_f32_32x32x16_bf16(paf2, vbf[2][1], O1, 0, 0, 0);\
    O0 = __builtin_amdgcn_mfma_f32_32x32x16_bf16(paf3, vbf[3][0], O0, 0, 0, 0);\
    O1 = __builtin_amdgcn_mfma_f32_32x32x16_bf16(paf3, vbf[3][1], O1, 0, 0, 0);\
    asm volatile("s_waitcnt vmcnt(" #VM_ ")" ::: "memory");                    \
    __builtin_amdgcn_s_barrier();                                              \
} while (0)

    STAGE(0, 0); STAGE(1, 1);
    asm volatile("s_waitcnt vmcnt(4)" ::: "memory");
    __builtin_amdgcn_s_barrier();

#pragma unroll 1
    for (int kt3 = 0; kt3 < 12; kt3 += 3) {
        ABODY(0, 2, kt3 + 0, 4);
        ABODY(1, 0, kt3 + 1, 4);
        ABODY(2, 1, kt3 + 2, 4);
    }
    ABODY(0, 2, 12, 4);
    ABODY(1, 0, 13, 4);
    ABODY(2, 1, 14, 0);
    ABODY(0, 2, 15, 0);
#undef ABODY
#undef STAGE

    float stot = sumacc + __shfl_xor(sumacc, 32, 64);
    float inv = 1.f / stot;
    if (l31 == lane) sinv[wid][l31] = inv;
    __syncthreads();

#pragma unroll
    for (int r = 0; r < 16; r++) {
        int qloc = (r & 3) + 8 * (r >> 2) + 4 * hi5;
        float iv = sinv[wid][qloc];
        size_t row = (size_t)(b * NN_ + q0 + qloc) * CC + h * HDD;
        AO[row + l31]      = f2bf(O0[r] * iv);
        AO[row + 32 + l31] = f2bf(O1[r] * iv);
    }
}

// ---------------------------------------------------------------- proj GEMM
// r3 structure + counted-vmcnt 3-buffer staging (same mechanism as attn).
__global__ __launch_bounds__(256)
void proj_gemm(const unsigned short* __restrict__ A,
               const unsigned short* __restrict__ Bt,
               const float* __restrict__ bias,
               float* __restrict__ Out) {
    __shared__ short sA[3][4096];
    __shared__ short sB[3][4096];
    const int K = 768;
    const int lane = threadIdx.x & 63;
    const int wid  = threadIdx.x >> 6;
    const int wr = wid >> 1, wc = wid & 1;
    const int brow = blockIdx.x * 128;
    const int bcol = blockIdx.y * 128;
    const int t = threadIdx.x;

    f32x4 acc[4][4];
#pragma unroll
    for (int m = 0; m < 4; m++)
#pragma unroll
        for (int n = 0; n < 4; n++) acc[m][n] = (f32x4){0.f, 0.f, 0.f, 0.f};

#define PSTG(buf_, kt_) do {                                                   \
    _Pragma("unroll")                                                          \
    for (int i = 0; i < 2; i++) {                                              \
        int tt  = i * 256 + t;                                                 \
        int row = tt >> 2;                                                     \
        int kc  = (tt & 3) * 8;                                                \
        GLDS(A  + (size_t)(brow + row) * K + (kt_) * 32 + kc,                  \
             &sA[buf_][(i * 256 + wid * 64) * 8]);                             \
        GLDS(Bt + (size_t)(bcol + row) * K + (kt_) * 32 + kc,                  \
             &sB[buf_][(i * 256 + wid * 64) * 8]);                             \
    }                                                                          \
} while (0)

#define PBODY(cb_, sb_, kt_, VM_) do {                                         \
    if ((kt_) + 2 < 24) PSTG(sb_, (kt_) + 2);                                  \
    bf16x8 af[4], bfg[4];                                                      \
    _Pragma("unroll")                                                          \
    for (int m = 0; m < 4; m++) {                                              \
        int r = wr * 64 + m * 16 + (lane & 15);                                \
        af[m] = *(const bf16x8*)&sA[cb_][r * 32 + (lane >> 4) * 8];            \
    }                                                                          \
    _Pragma("unroll")                                                          \
    for (int n = 0; n < 4; n++) {                                              \
        int cc2 = wc * 64 + n * 16 + (lane & 15);                              \
        bfg[n] = *(const bf16x8*)&sB[cb_][cc2 * 32 + (lane >> 4) * 8];         \
    }                                                                          \
    _Pragma("unroll")                                                          \
    for (int m = 0; m < 4; m++)                                                \
        _Pragma("unroll")                                                      \
        for (int n = 0; n < 4; n++)                                            \
            acc[m][n] = __builtin_amdgcn_mfma_f32_16x16x32_bf16(af[m], bfg[n], acc[m][n], 0, 0, 0); \
    asm volatile("s_waitcnt vmcnt(" #VM_ ")" ::: "memory");                    \
    __builtin_amdgcn_s_barrier();                                              \
} while (0)

    PSTG(0, 0); PSTG(1, 1);
    asm volatile("s_waitcnt vmcnt(4)" ::: "memory");
    __builtin_amdgcn_s_barrier();

#pragma unroll 1
    for (int kt3 = 0; kt3 < 21; kt3 += 3) {
        PBODY(0, 2, kt3 + 0, 4);
        PBODY(1, 0, kt3 + 1, 4);
        PBODY(2, 1, kt3 + 2, 4);
    }
    PBODY(0, 2, 21, 4);
    PBODY(1, 0, 22, 0);
    PBODY(2, 1, 23, 0);
#undef PBODY
#undef PSTG

#pragma unroll
    for (int m = 0; m < 4; m++)
#pragma unroll
        for (int n = 0; n < 4; n++) {
            int col = bcol + wc * 64 + n * 16 + (lane & 15);
            float bv = bias[col];
#pragma unroll
            for (int r = 0; r < 4; r++) {
                int row = brow + wr * 64 + m * 16 + (lane >> 4) * 4 + r;
                Out[(size_t)row * 768 + col] = acc[m][n][r] + bv;
            }
        }
}

// ---------------------------------------------------------------- launcher
extern "C" void kernel_launch(void* const* d_in, const int* in_sizes, int n_in,
                              void* d_out, int out_size, void* d_ws, size_t ws_size,
                              hipStream_t stream) {
    const float* x     = (const float*)d_in[0];
    const float* Wqkv  = (const float*)d_in[1];
    const float* Wfc1  = (const float*)d_in[2];
    const float* bfc1  = (const float*)d_in[3];
    const float* Wfc2  = (const float*)d_in[4];
    const float* bfc2  = (const float*)d_in[5];
    const float* Wproj = (const float*)d_in[6];
    const float* bproj = (const float*)d_in[7];
    float* out = (float*)d_out;

    char* ws = (char*)d_ws;
    const size_t SZ_XN = (size_t)8192 * 768 * 2;                 // 12.58 MB
    unsigned short* x_bf    = (unsigned short*)ws; ws += SZ_XN;  // reused as attn_out
    unsigned short* wqkv_bf = (unsigned short*)ws; ws += (size_t)2304 * 768 * 2;
    unsigned short* wproj_bf= (unsigned short*)ws; ws += (size_t)768 * 768 * 2;
    unsigned short* wfc1_bf = (unsigned short*)ws; ws += 64 * 64 * 2;
    unsigned short* wfc2_bf = (unsigned short*)ws; ws += 64 * 64 * 2;
    unsigned short* Rq      = (unsigned short*)ws; ws += SZ_XN;  // Q_spk [b,h][n][d]
    unsigned short* Rk      = (unsigned short*)ws; ws += SZ_XN;  // K_spk [b,h][n][d]
    unsigned short* VT      = (unsigned short*)ws; ws += SZ_XN;  // V_rec [b,h][d][n]

    cvt_all<<<2048, 256, 0, stream>>>(x, Wqkv, Wproj, Wfc1, Wfc2,
                                      x_bf, wqkv_bf, wproj_bf, wfc1_bf, wfc2_bf);
    qkv_spk_gemm<<<576, 512, 0, stream>>>(x_bf, wqkv_bf, wfc1_bf, wfc2_bf,
                                          bfc1, bfc2, Rq, Rk, VT);
    attn_kernel<<<768, 256, 0, stream>>>(Rq, Rk, VT, x_bf);
    proj_gemm<<<dim3(64, 6), 256, 0, stream>>>(x_bf, wproj_bf, bproj, out);
}

// Round 11
// 132.997 us; speedup vs baseline: 1.7711x; 1.7711x over previous
//
#include <hip/hip_runtime.h>
#include <hip/hip_bf16.h>
#include <stdint.h>
#include <math.h>

// Sizes fixed by the problem.
#define BB   8
#define NN_  1024
#define CC   768
#define HH   12
#define HDD  64

typedef __attribute__((ext_vector_type(8))) short bf16x8;   // 8 bf16 (4 VGPRs)
typedef __attribute__((ext_vector_type(4))) float f32x4;    // 16x16 MFMA acc
typedef __attribute__((ext_vector_type(16))) float f32x16;  // 32x32 MFMA acc
typedef __attribute__((ext_vector_type(4))) float f32x4v;
typedef __attribute__((ext_vector_type(4))) unsigned short u16x4;

union FragU { unsigned int u[4]; bf16x8 b; };

__device__ __forceinline__ unsigned short f2bf(float f) {
    union { float f; unsigned int u; } v; v.f = f;
    unsigned int r = v.u + 0x7fffu + ((v.u >> 16) & 1u);   // RNE
    return (unsigned short)(r >> 16);
}

#define CVTPK(d_, a_, b_) asm("v_cvt_pk_bf16_f32 %0, %1, %2" : "=v"(d_) : "v"(a_), "v"(b_))
#define SWAP32(a_, b_) asm("v_permlane32_swap_b32 %0, %1" : "+v"(a_), "+v"(b_))

#define GLDS(g_, l_) __builtin_amdgcn_global_load_lds( \
    (const __attribute__((address_space(1))) void*)(g_), \
    (__attribute__((address_space(3))) void*)(l_), 16, 0, 0)

// Transform a 32x32 C'-tile (col=lane&31, crow=(r&3)+8*(r>>2)+4*hi5) held as
// 16 lane-local floats into two bf16 A-frags [row=col][k=crow 0..15 / 16..31].
#define MKFRAGS(P_, F0_, F1_) do {                                             \
    unsigned int c0,c1,c2,c3,c4,c5,c6,c7;                                      \
    CVTPK(c0, P_[0],  P_[1]);  CVTPK(c1, P_[2],  P_[3]);                       \
    CVTPK(c2, P_[4],  P_[5]);  CVTPK(c3, P_[6],  P_[7]);                       \
    CVTPK(c4, P_[8],  P_[9]);  CVTPK(c5, P_[10], P_[11]);                      \
    CVTPK(c6, P_[12], P_[13]); CVTPK(c7, P_[14], P_[15]);                      \
    SWAP32(c0, c2); SWAP32(c1, c3); SWAP32(c4, c6); SWAP32(c5, c7);            \
    FragU fu0_, fu1_;                                                          \
    fu0_.u[0]=c0; fu0_.u[1]=c1; fu0_.u[2]=c2; fu0_.u[3]=c3;                    \
    fu1_.u[0]=c4; fu1_.u[1]=c5; fu1_.u[2]=c6; fu1_.u[3]=c7;                    \
    F0_ = fu0_.b; F1_ = fu1_.b;                                                \
} while (0)

// ---------------------------------------------------------------- fused cvt
#define CVT_N0 1572864   // x
#define CVT_N1 2015232   // +Wqkv
#define CVT_N2 2162688   // +Wproj
#define CVT_N3 2163712   // +Wfc1
#define CVT_N4 2164736   // +Wfc2
__global__ void cvt_all(const float* __restrict__ x, const float* __restrict__ wqkv,
                        const float* __restrict__ wproj, const float* __restrict__ wf1,
                        const float* __restrict__ wf2,
                        unsigned short* __restrict__ xb, unsigned short* __restrict__ wqkvb,
                        unsigned short* __restrict__ wprojb, unsigned short* __restrict__ wf1b,
                        unsigned short* __restrict__ wf2b) {
    int i = blockIdx.x * blockDim.x + threadIdx.x;
    int stride = gridDim.x * blockDim.x;
    for (; i < CVT_N4; i += stride) {
        const f32x4v* src; u16x4* dst; int off;
        if (i < CVT_N0)      { src = (const f32x4v*)x;     dst = (u16x4*)xb;     off = i; }
        else if (i < CVT_N1) { src = (const f32x4v*)wqkv;  dst = (u16x4*)wqkvb;  off = i - CVT_N0; }
        else if (i < CVT_N2) { src = (const f32x4v*)wproj; dst = (u16x4*)wprojb; off = i - CVT_N1; }
        else if (i < CVT_N3) { src = (const f32x4v*)wf1;   dst = (u16x4*)wf1b;   off = i - CVT_N2; }
        else                 { src = (const f32x4v*)wf2;   dst = (u16x4*)wf2b;   off = i - CVT_N3; }
        f32x4v v = src[off];
        u16x4 o;
        o.x = f2bf(v.x); o.y = f2bf(v.y); o.z = f2bf(v.z); o.w = f2bf(v.w);
        dst[off] = o;
    }
}

// ---------------------------------------------------------------- QKV+spk GEMM
// r9 version (best measured: 57.1us). 4-buf counted-vmcnt + read-ahead, X
// staged through LDS, L2-reuse-swapped XCD mapping. r10's X-direct-gather
// REFUTED (167us, 4x over-fetch from 1536B-strided lane rows) — do not retry.
__global__ __launch_bounds__(512, 1)
void qkv_spk_gemm(const unsigned short* __restrict__ X,
                  const unsigned short* __restrict__ Wqkv,
                  const unsigned short* __restrict__ Wf1,
                  const unsigned short* __restrict__ Wf2,
                  const float* __restrict__ bf1,
                  const float* __restrict__ bf2,
                  unsigned short* __restrict__ Rq,
                  unsigned short* __restrict__ Rk,
                  unsigned short* __restrict__ VT) {
    __shared__ short sA[4][8192];   // 4 x 16KB: 256 feat x 32 k
    __shared__ short sB[4][4096];   // 4 x  8KB: 128 tok  x 32 k   total 96KB

    const int t    = threadIdx.x;       // 0..511
    const int wid  = t >> 6;            // 0..7
    const int lane = t & 63;
    const int l31  = lane & 31;
    const int hi5  = lane >> 5;
    const int fw   = wid >> 1;          // feat quarter 0..3 (64 feats each)
    const int wn   = wid & 1;           // tok half 0..1 (64 tokens each)

    // L2-reuse-swapped XCD mapping (bijective over 576 = 8 XCD x 8 g x 9 f):
    const int bid  = (int)blockIdx.x;
    const int c    = bid & 7;           // XCD
    const int j    = bid >> 3;          // 0..71
    const int f_   = j % 9;             // feature panel (inner -> X stays hot)
    const int g_   = j / 9;             // token tile within XCD
    const int bx   = c * 8 + g_;        // token tile (128 tokens), 0..63
    const int by   = f_;                // feature tile (256 features), 0..8
    const int F0   = by * 256;
    const int T0   = bx * 128;

#define STG(bi_, kt_) do {                                                     \
    _Pragma("unroll")                                                          \
    for (int i = 0; i < 2; i++) {                                              \
        int li_ = i * 512 + t;                                                 \
        int dr_ = li_ >> 3;                                                    \
        int u_  = (li_ & 7) ^ (dr_ & 7);                                       \
        GLDS(Wqkv + (size_t)(F0 + dr_ * 2 + (u_ >> 2)) * 768 + (kt_) * 32 + (u_ & 3) * 8, \
             &sA[bi_][li_ * 8]);                                               \
    }                                                                          \
    {                                                                          \
        int dr_ = t >> 3;                                                      \
        int u_  = (t & 7) ^ (dr_ & 7);                                         \
        GLDS(X + (size_t)(T0 + dr_ * 2 + (u_ >> 2)) * 768 + (kt_) * 32 + (u_ & 3) * 8, \
             &sB[bi_][t * 8]);                                                 \
    }                                                                          \
} while (0)

    f32x16 acc[2][2];
#pragma unroll
    for (int fb = 0; fb < 2; fb++)
#pragma unroll
        for (int tb = 0; tb < 2; tb++)
#pragma unroll
            for (int r = 0; r < 16; r++) acc[fb][tb][r] = 0.f;

    bf16x8 wA[2][2], xA[2][2], wB[2][2], xB[2][2];   // named sets (rule #20)

#define RD(W_, X_, bc_) do {                                                   \
    const char* ab_ = (const char*)sA[bc_];                                    \
    const char* bb_ = (const char*)sB[bc_];                                    \
    _Pragma("unroll")                                                          \
    for (int fb = 0; fb < 2; fb++) {                                           \
        int r_ = fw * 64 + fb * 32 + l31;                                      \
        int dr_ = r_ >> 1;                                                     \
        _Pragma("unroll")                                                      \
        for (int ks = 0; ks < 2; ks++)                                         \
            W_[fb][ks] = *(const bf16x8*)(ab_ + dr_ * 128 +                    \
                ((((r_ & 1) * 4 + ks * 2 + hi5) ^ (dr_ & 7)) << 4));           \
    }                                                                          \
    _Pragma("unroll")                                                          \
    for (int tb = 0; tb < 2; tb++) {                                           \
        int r_ = wn * 64 + tb * 32 + l31;                                      \
        int dr_ = r_ >> 1;                                                     \
        _Pragma("unroll")                                                      \
        for (int ks = 0; ks < 2; ks++)                                         \
            X_[tb][ks] = *(const bf16x8*)(bb_ + dr_ * 128 +                    \
                ((((r_ & 1) * 4 + ks * 2 + hi5) ^ (dr_ & 7)) << 4));           \
    }                                                                          \
} while (0)

#define MFMA8(W_, X_)                                                          \
    _Pragma("unroll")                                                          \
    for (int ks = 0; ks < 2; ks++)                                             \
        _Pragma("unroll")                                                      \
        for (int fb = 0; fb < 2; fb++)                                         \
            _Pragma("unroll")                                                  \
            for (int tb = 0; tb < 2; tb++)                                     \
                acc[fb][tb] = __builtin_amdgcn_mfma_f32_32x32x16_bf16(         \
                    W_[fb][ks], X_[tb][ks], acc[fb][tb], 0, 0, 0)

#define PH(CW_, CX_, NW_, NX_, rb_, sb_, t_, VM_) do {                         \
    if ((t_) + 3 < 24) STG(sb_, (t_) + 3);                                     \
    asm volatile("s_waitcnt vmcnt(" #VM_ ")" ::: "memory");                    \
    __builtin_amdgcn_s_barrier();                                              \
    if ((t_) + 1 < 24) RD(NW_, NX_, rb_);                                      \
    __builtin_amdgcn_sched_barrier(0);                                         \
    __builtin_amdgcn_s_setprio(1);                                             \
    MFMA8(CW_, CX_);                                                           \
    __builtin_amdgcn_s_setprio(0);                                             \
    asm volatile("s_waitcnt lgkmcnt(0)" ::: "memory");                         \
} while (0)

    STG(0, 0); STG(1, 1); STG(2, 2);
    asm volatile("s_waitcnt vmcnt(6)" ::: "memory");
    __builtin_amdgcn_s_barrier();
    RD(wA, xA, 0);
    asm volatile("s_waitcnt lgkmcnt(0)" ::: "memory");

#pragma unroll 1
    for (int t4 = 0; t4 < 20; t4 += 4) {
        PH(wA, xA, wB, xB, 1, 3, t4 + 0, 6);
        PH(wB, xB, wA, xA, 2, 0, t4 + 1, 6);
        PH(wA, xA, wB, xB, 3, 1, t4 + 2, 6);
        PH(wB, xB, wA, xA, 0, 2, t4 + 3, 6);
    }
    PH(wA, xA, wB, xB, 1, 3, 20, 6);
    PH(wB, xB, wA, xA, 2, 0, 21, 3);
    PH(wA, xA, wB, xB, 3, 1, 22, 0);
    PH(wB, xB, wA, xA, 0, 2, 23, 0);
#undef PH
#undef MFMA8
#undef RD
#undef STG

    // ---- epilogue (r5-r9 validated, wave = 64 feat x 64 tok) ----
    const int fbase = F0 + fw * 64;
    const int p  = fbase / 768;
    const int hh = (fbase - p * 768) >> 6;
    const int tok0 = T0 + wn * 64;       // 64-aligned -> single batch
    const int b  = tok0 >> 10;
    const int n0 = tok0 & 1023;
    const int crow0 = 4 * hi5;

    if (p == 2) {
        const size_t vtb = ((size_t)(b * HH + hh)) * HDD * NN_;
#pragma unroll
        for (int fb = 0; fb < 2; fb++)
#pragma unroll
            for (int tb = 0; tb < 2; tb++)
#pragma unroll
                for (int r = 0; r < 16; r++) {
                    int d = fb * 32 + (r & 3) + 8 * (r >> 2) + crow0;
                    int n = n0 + tb * 32 + l31;
                    VT[vtb + (size_t)d * NN_ + n] = f2bf(4.f * fmaxf(acc[fb][tb][r], 0.f));
                }
    } else {
        const unsigned short* Wf = p ? Wf2 : Wf1;
        const float* bfp = p ? bf2 : bf1;
        unsigned short* R = p ? Rk : Rq;
        bf16x8 wfr[2][4];
#pragma unroll
        for (int dh = 0; dh < 2; dh++)
#pragma unroll
            for (int ks = 0; ks < 4; ks++)
                wfr[dh][ks] = *(const bf16x8*)&Wf[(size_t)(dh * 32 + l31) * HDD + ks * 16 + hi5 * 8];
        float bv0 = bfp[l31], bv1 = bfp[32 + l31];
        const size_t qkb = ((size_t)(b * HH + hh)) * NN_ * HDD;
#pragma unroll
        for (int tb = 0; tb < 2; tb++) {
            float pv0[16], pv1[16];
#pragma unroll
            for (int r = 0; r < 16; r++) {
                pv0[r] = fmaxf(acc[0][tb][r], 0.f);
                pv1[r] = fmaxf(acc[1][tb][r], 0.f);
            }
            bf16x8 pa0, pa1, pa2, pa3;
            MKFRAGS(pv0, pa0, pa1);
            MKFRAGS(pv1, pa2, pa3);
            f32x16 D0, D1;
#pragma unroll
            for (int r = 0; r < 16; r++) { D0[r] = 0.f; D1[r] = 0.f; }
            D0 = __builtin_amdgcn_mfma_f32_32x32x16_bf16(pa0, wfr[0][0], D0, 0, 0, 0);
            D0 = __builtin_amdgcn_mfma_f32_32x32x16_bf16(pa1, wfr[0][1], D0, 0, 0, 0);
            D0 = __builtin_amdgcn_mfma_f32_32x32x16_bf16(pa2, wfr[0][2], D0, 0, 0, 0);
            D0 = __builtin_amdgcn_mfma_f32_32x32x16_bf16(pa3, wfr[0][3], D0, 0, 0, 0);
            D1 = __builtin_amdgcn_mfma_f32_32x32x16_bf16(pa0, wfr[1][0], D1, 0, 0, 0);
            D1 = __builtin_amdgcn_mfma_f32_32x32x16_bf16(pa1, wfr[1][1], D1, 0, 0, 0);
            D1 = __builtin_amdgcn_mfma_f32_32x32x16_bf16(pa2, wfr[1][2], D1, 0, 0, 0);
            D1 = __builtin_amdgcn_mfma_f32_32x32x16_bf16(pa3, wfr[1][3], D1, 0, 0, 0);
#pragma unroll
            for (int r = 0; r < 16; r++) {
                int n = n0 + tb * 32 + (r & 3) + 8 * (r >> 2) + crow0;
                size_t rowb = qkb + (size_t)n * HDD;
                R[rowb + l31]      = f2bf(D0[r] + bv0);
                R[rowb + 32 + l31] = f2bf(D1[r] + bv1);
            }
        }
    }
}

// ---------------------------------------------------------------- attention
// r10 version (counted-vmcnt 3-buffer; measured neutral-to-positive) — kept.
__global__ __launch_bounds__(256, 2)
void attn_kernel(const unsigned short* __restrict__ Q,
                 const unsigned short* __restrict__ Kx,
                 const unsigned short* __restrict__ VT,
                 unsigned short* __restrict__ AO) {
    __shared__ short sK[3][4096];
    __shared__ short sV[3][4096];
    __shared__ float sinv[4][32];

    const int t    = threadIdx.x;
    const int lane = t & 63;
    const int wid  = t >> 6;
    const int l31  = lane & 31;
    const int hi5  = lane >> 5;

    const int bid = (int)blockIdx.x;
    const int lbid = (bid & 7) * 96 + (bid >> 3);
    const int bh = lbid >> 3;
    const int qt = lbid & 7;
    const int b = bh / HH, h = bh - b * HH;

    const unsigned short* Qs = Q  + (size_t)bh * NN_ * HDD;
    const unsigned short* Ks = Kx + (size_t)bh * NN_ * HDD;
    const unsigned short* Vt = VT + (size_t)bh * HDD * NN_;
    const int q0 = qt * 128 + wid * 32;

    bf16x8 qf[4];
#pragma unroll
    for (int ds = 0; ds < 4; ds++)
        qf[ds] = *(const bf16x8*)&Qs[(size_t)(q0 + l31) * HDD + ds * 16 + hi5 * 8];

    f32x16 O0, O1;
#pragma unroll
    for (int r = 0; r < 16; r++) { O0[r] = 0.f; O1[r] = 0.f; }
    float sumacc = 0.f;

    const int srow = t >> 3;
    const int sslot = t & 7;
    const int dstoff = ((t & 192)) * 8;

#define STAGE(buf_, kt_) do {                                                  \
    _Pragma("unroll")                                                          \
    for (int i = 0; i < 2; i++) {                                              \
        int row_ = srow + i * 32;                                              \
        int sl_  = (sslot ^ (row_ & 7)) << 3;                                  \
        const unsigned short* gk_ = Ks + (size_t)((kt_) * 64 + row_) * HDD + sl_; \
        const unsigned short* gv_ = Vt + (size_t)row_ * NN_ + (kt_) * 64 + sl_;   \
        GLDS(gk_, &sK[buf_][i * 2048 + dstoff]);                               \
        GLDS(gv_, &sV[buf_][i * 2048 + dstoff]);                               \
    }                                                                          \
} while (0)

#define ABODY(cb_, sb_, kt_, VM_) do {                                         \
    if ((kt_) + 2 < 16) STAGE(sb_, (kt_) + 2);                                 \
    const char* kbase = (const char*)&sK[cb_][0];                              \
    const char* vbase = (const char*)&sV[cb_][0];                              \
    bf16x8 vbf[4][2];                                                          \
    _Pragma("unroll")                                                          \
    for (int ks = 0; ks < 4; ks++)                                             \
        _Pragma("unroll")                                                      \
        for (int dt = 0; dt < 2; dt++) {                                       \
            int d = dt * 32 + l31;                                             \
            vbf[ks][dt] = *(const bf16x8*)(vbase + d * 128 +                   \
                           ((ks * 32 + hi5 * 16) ^ ((d & 7) << 4)));           \
        }                                                                      \
    bf16x8 ka[2][4];                                                           \
    _Pragma("unroll")                                                          \
    for (int kt2 = 0; kt2 < 2; kt2++)                                          \
        _Pragma("unroll")                                                      \
        for (int ds = 0; ds < 4; ds++) {                                       \
            int kk = kt2 * 32 + l31;                                           \
            ka[kt2][ds] = *(const bf16x8*)(kbase + kk * 128 +                  \
                           ((ds * 32 + hi5 * 16) ^ ((kk & 7) << 4)));          \
        }                                                                      \
    f32x16 S0, S1;                                                             \
    _Pragma("unroll")                                                          \
    for (int r = 0; r < 16; r++) { S0[r] = 0.f; S1[r] = 0.f; }                 \
    _Pragma("unroll")                                                          \
    for (int ds = 0; ds < 4; ds++) {                                           \
        S0 = __builtin_amdgcn_mfma_f32_32x32x16_bf16(ka[0][ds], qf[ds], S0, 0, 0, 0); \
        S1 = __builtin_amdgcn_mfma_f32_32x32x16_bf16(ka[1][ds], qf[ds], S1, 0, 0, 0); \
    }                                                                          \
    float p0[16], p1[16];                                                      \
    _Pragma("unroll")                                                          \
    for (int r = 0; r < 16; r++) {                                             \
        p0[r] = exp2f(0.36067376f * fmaxf(S0[r], 0.f));                        \
        p1[r] = exp2f(0.36067376f * fmaxf(S1[r], 0.f));                        \
    }                                                                          \
    float s0 = 0.f, s1 = 0.f;                                                  \
    _Pragma("unroll")                                                          \
    for (int r = 0; r < 16; r++) { s0 += p0[r]; s1 += p1[r]; }                 \
    sumacc += s0 + s1;                                                         \
    bf16x8 paf0, paf1, paf2, paf3;                                             \
    MKFRAGS(p0, paf0, paf1);                                                   \
    MKFRAGS(p1, paf2, paf3);                                                   \
    O0 = __builtin_amdgcn_mfma_f32_32x32x16_bf16(paf0, vbf[0][0], O0, 0, 0, 0);\
    O1 = __builtin_amdgcn_mfma_f32_32x32x16_bf16(paf0, vbf[0][1], O1, 0, 0, 0);\
    O0 = __builtin_amdgcn_mfma_f32_32x32x16_bf16(paf1, vbf[1][0], O0, 0, 0, 0);\
    O1 = __builtin_amdgcn_mfma_f32_32x32x16_bf16(paf1, vbf[1][1], O1, 0, 0, 0);\
    O0 = __builtin_amdgcn_mfma_f32_32x32x16_bf16(paf2, vbf[2][0], O0, 0, 0, 0);\
    O1 = __builtin_amdgcn_mfma_f32_32x32x16_bf16(paf2, vbf[2][1], O1, 0, 0, 0);\
    O0 = __builtin_amdgcn_mfma_f32_32x32x16_bf16(paf3, vbf[3][0], O0, 0, 0, 0);\
    O1 = __builtin_amdgcn_mfma_f32_32x32x16_bf16(paf3, vbf[3][1], O1, 0, 0, 0);\
    asm volatile("s_waitcnt vmcnt(" #VM_ ")" ::: "memory");                    \
    __builtin_amdgcn_s_barrier();                                              \
} while (0)

    STAGE(0, 0); STAGE(1, 1);
    asm volatile("s_waitcnt vmcnt(4)" ::: "memory");
    __builtin_amdgcn_s_barrier();

#pragma unroll 1
    for (int kt3 = 0; kt3 < 12; kt3 += 3) {
        ABODY(0, 2, kt3 + 0, 4);
        ABODY(1, 0, kt3 + 1, 4);
        ABODY(2, 1, kt3 + 2, 4);
    }
    ABODY(0, 2, 12, 4);
    ABODY(1, 0, 13, 4);
    ABODY(2, 1, 14, 0);
    ABODY(0, 2, 15, 0);
#undef ABODY
#undef STAGE

    float stot = sumacc + __shfl_xor(sumacc, 32, 64);
    float inv = 1.f / stot;
    if (l31 == lane) sinv[wid][l31] = inv;
    __syncthreads();

#pragma unroll
    for (int r = 0; r < 16; r++) {
        int qloc = (r & 3) + 8 * (r >> 2) + 4 * hi5;
        float iv = sinv[wid][qloc];
        size_t row = (size_t)(b * NN_ + q0 + qloc) * CC + h * HDD;
        AO[row + l31]      = f2bf(O0[r] * iv);
        AO[row + 32 + l31] = f2bf(O1[r] * iv);
    }
}

// ---------------------------------------------------------------- proj GEMM
// r10 version (counted-vmcnt 3-buffer) — kept.
__global__ __launch_bounds__(256)
void proj_gemm(const unsigned short* __restrict__ A,
               const unsigned short* __restrict__ Bt,
               const float* __restrict__ bias,
               float* __restrict__ Out) {
    __shared__ short sA[3][4096];
    __shared__ short sB[3][4096];
    const int K = 768;
    const int lane = threadIdx.x & 63;
    const int wid  = threadIdx.x >> 6;
    const int wr = wid >> 1, wc = wid & 1;
    const int brow = blockIdx.x * 128;
    const int bcol = blockIdx.y * 128;
    const int t = threadIdx.x;

    f32x4 acc[4][4];
#pragma unroll
    for (int m = 0; m < 4; m++)
#pragma unroll
        for (int n = 0; n < 4; n++) acc[m][n] = (f32x4){0.f, 0.f, 0.f, 0.f};

#define PSTG(buf_, kt_) do {                                                   \
    _Pragma("unroll")                                                          \
    for (int i = 0; i < 2; i++) {                                              \
        int tt  = i * 256 + t;                                                 \
        int row = tt >> 2;                                                     \
        int kc  = (tt & 3) * 8;                                                \
        GLDS(A  + (size_t)(brow + row) * K + (kt_) * 32 + kc,                  \
             &sA[buf_][(i * 256 + wid * 64) * 8]);                             \
        GLDS(Bt + (size_t)(bcol + row) * K + (kt_) * 32 + kc,                  \
             &sB[buf_][(i * 256 + wid * 64) * 8]);                             \
    }                                                                          \
} while (0)

#define PBODY(cb_, sb_, kt_, VM_) do {                                         \
    if ((kt_) + 2 < 24) PSTG(sb_, (kt_) + 2);                                  \
    bf16x8 af[4], bfg[4];                                                      \
    _Pragma("unroll")                                                          \
    for (int m = 0; m < 4; m++) {                                              \
        int r = wr * 64 + m * 16 + (lane & 15);                                \
        af[m] = *(const bf16x8*)&sA[cb_][r * 32 + (lane >> 4) * 8];            \
    }                                                                          \
    _Pragma("unroll")                                                          \
    for (int n = 0; n < 4; n++) {                                              \
        int cc2 = wc * 64 + n * 16 + (lane & 15);                              \
        bfg[n] = *(const bf16x8*)&sB[cb_][cc2 * 32 + (lane >> 4) * 8];         \
    }                                                                          \
    _Pragma("unroll")                                                          \
    for (int m = 0; m < 4; m++)                                                \
        _Pragma("unroll")                                                      \
        for (int n = 0; n < 4; n++)                                            \
            acc[m][n] = __builtin_amdgcn_mfma_f32_16x16x32_bf16(af[m], bfg[n], acc[m][n], 0, 0, 0); \
    asm volatile("s_waitcnt vmcnt(" #VM_ ")" ::: "memory");                    \
    __builtin_amdgcn_s_barrier();                                              \
} while (0)

    PSTG(0, 0); PSTG(1, 1);
    asm volatile("s_waitcnt vmcnt(4)" ::: "memory");
    __builtin_amdgcn_s_barrier();

#pragma unroll 1
    for (int kt3 = 0; kt3 < 21; kt3 += 3) {
        PBODY(0, 2, kt3 + 0, 4);
        PBODY(1, 0, kt3 + 1, 4);
        PBODY(2, 1, kt3 + 2, 4);
    }
    PBODY(0, 2, 21, 4);
    PBODY(1, 0, 22, 0);
    PBODY(2, 1, 23, 0);
#undef PBODY
#undef PSTG

#pragma unroll
    for (int m = 0; m < 4; m++)
#pragma unroll
        for (int n = 0; n < 4; n++) {
            int col = bcol + wc * 64 + n * 16 + (lane & 15);
            float bv = bias[col];
#pragma unroll
            for (int r = 0; r < 4; r++) {
                int row = brow + wr * 64 + m * 16 + (lane >> 4) * 4 + r;
                Out[(size_t)row * 768 + col] = acc[m][n][r] + bv;
            }
        }
}

// ---------------------------------------------------------------- launcher
extern "C" void kernel_launch(void* const* d_in, const int* in_sizes, int n_in,
                              void* d_out, int out_size, void* d_ws, size_t ws_size,
                              hipStream_t stream) {
    const float* x     = (const float*)d_in[0];
    const float* Wqkv  = (const float*)d_in[1];
    const float* Wfc1  = (const float*)d_in[2];
    const float* bfc1  = (const float*)d_in[3];
    const float* Wfc2  = (const float*)d_in[4];
    const float* bfc2  = (const float*)d_in[5];
    const float* Wproj = (const float*)d_in[6];
    const float* bproj = (const float*)d_in[7];
    float* out = (float*)d_out;

    char* ws = (char*)d_ws;
    const size_t SZ_XN = (size_t)8192 * 768 * 2;                 // 12.58 MB
    unsigned short* x_bf    = (unsigned short*)ws; ws += SZ_XN;  // reused as attn_out
    unsigned short* wqkv_bf = (unsigned short*)ws; ws += (size_t)2304 * 768 * 2;
    unsigned short* wproj_bf= (unsigned short*)ws; ws += (size_t)768 * 768 * 2;
    unsigned short* wfc1_bf = (unsigned short*)ws; ws += 64 * 64 * 2;
    unsigned short* wfc2_bf = (unsigned short*)ws; ws += 64 * 64 * 2;
    unsigned short* Rq      = (unsigned short*)ws; ws += SZ_XN;  // Q_spk [b,h][n][d]
    unsigned short* Rk      = (unsigned short*)ws; ws += SZ_XN;  // K_spk [b,h][n][d]
    unsigned short* VT      = (unsigned short*)ws; ws += SZ_XN;  // V_rec [b,h][d][n]

    cvt_all<<<2048, 256, 0, stream>>>(x, Wqkv, Wproj, Wfc1, Wfc2,
                                      x_bf, wqkv_bf, wproj_bf, wfc1_bf, wfc2_bf);
    qkv_spk_gemm<<<576, 512, 0, stream>>>(x_bf, wqkv_bf, wfc1_bf, wfc2_bf,
                                          bfc1, bfc2, Rq, Rk, VT);
    attn_kernel<<<768, 256, 0, stream>>>(Rq, Rk, VT, x_bf);
    proj_gemm<<<dim3(64, 6), 256, 0, stream>>>(x_bf, wproj_bf, bproj, out);
}